// Round 17
// baseline (290.336 us; speedup 1.0000x reference)
//
#include <hip/hip_runtime.h>
#include <hip/hip_bf16.h>
#include <cstdint>
#include <cstddef>

// out[B,OUT] = (x * alpha) @ W,  W[i,o] = exp(-||col_i - row_o||^2)
// B=8192, IN=4096, OUT=4096.  f32 in/out.
//
// r17: B NEVER TOUCHES LDS.  Pipe accounting showed LDS was the critical
// pipe (~3300 cy/tile vs MFMA 2483): we build W ourselves, so prep emits it
// in MFMA FRAGMENT ORDER (Wt2[panel][kt][frag][kk][lane][8 bf16]) and the
// GEMM loads each B fragment as ONE coalesced 1KB global_load_dwordx4 into
// registers, double-buffered one tile ahead.  Removes 64KB LDS reads + 32KB
// LDS writes + 32 gload_lds per CU-tile; LDS (A only, 64KB) drops to
// ~1750cy/tile, MFMA (2483cy) becomes co-critical.
//
// Per tile t (A buf BO = (t&1)*16384; 1 barrier/tile):
//   LOADB(t+1) -> bNext (8 reg loads)
//   vmcnt(8)   -- confirms B(t) regs [issued t-1, ~1 tile old] AND A(t) LDS
//                 [staged t-1 post-barrier]; leaves B(t+1) in flight. 0-stall.
//   barrier    -- A(t) visible to all waves
//   STAGE_A(t+1) -> buf^1 (4 gload_lds)  [post-barrier => WAR-safe: buf^1's
//                 last reads were t-1 pre-barrier]
//   read afL (8 ds); MFMA afL x bCur (32); read afH; MFMA afH x bCur (32)
// Unroll x2 ping-pongs bCur/bNext (static reg indexing).  Tail: clamped
// re-loads/stages target dead regs/buffer (benign).  Trailing vmcnt(0).
//
// Wt2 fragment layout (16x16x32 B-frag: lane l = lh*16+lr holds
// W[col=lr][k=kk*32+lh*8 .. +7]):  elem index =
//   ((panel*64 + kt)*16 + wn*4+nf)*1024 + kk*512 + lane*8
// prep writes each bf16x8 chunk (8 consecutive k of one col) to that address.
// A-side LDS layout/swizzle unchanged (0 conflicts since r5).

#define IN_DIM  4096
#define OUT_DIM 4096
#define BATCH   8192

#define BM 256
#define BN 256
#define BK 64
#define KTILES (IN_DIM / BK)   // 64
#define THREADS 512

#define UNIT    8192           // elems per A stage unit (128 rows * 64)
#define ABUF    16384          // elems per A buffer (256 x 64)

#define NCONV  (BATCH * IN_DIM / (256 * 8))   // 16384 convert blocks
#define NWTB   (OUT_DIM * 2)                  // 8192 wt blocks

typedef __bf16 bf16x8 __attribute__((ext_vector_type(8)));
typedef float  f32x4  __attribute__((ext_vector_type(4)));

// ---------------------------------------------------------------------------
// Fused prep: blocks [0,NCONV) convert x; blocks [NCONV,NCONV+NWTB) build Wt2
// in MFMA-fragment order.
// ---------------------------------------------------------------------------
__global__ __launch_bounds__(256) void prep_kernel(
    const float* __restrict__ x,
    const float* __restrict__ rows_mean,     // [OUT,2]
    const float* __restrict__ columns_mean,  // [IN,2]
    const float* __restrict__ alpha,         // [IN]
    __bf16* __restrict__ xb,                 // [BATCH][IN]
    __bf16* __restrict__ Wt2)                // fragment-ordered W^T
{
    const int b = blockIdx.x;
    if (b < NCONV) {
        const size_t i = ((size_t)b * 256 + threadIdx.x) * 8;
        const float4 v0 = *(const float4*)(x + i);
        const float4 v1 = *(const float4*)(x + i + 4);
        bf16x8 o;
        o[0] = (__bf16)v0.x; o[1] = (__bf16)v0.y; o[2] = (__bf16)v0.z; o[3] = (__bf16)v0.w;
        o[4] = (__bf16)v1.x; o[5] = (__bf16)v1.y; o[6] = (__bf16)v1.z; o[7] = (__bf16)v1.w;
        *(bf16x8*)(xb + i) = o;
    } else {
        const int bb = b - NCONV;
        const int o  = bb >> 1;                          // output col 0..4095
        const int i0 = ((bb & 1) * 256 + threadIdx.x) * 8;  // k base

        const float r0 = rows_mean[2 * o];
        const float r1 = rows_mean[2 * o + 1];

        const float4* cm = (const float4*)(columns_mean + 2 * (size_t)i0);
        float4 c01 = cm[0], c23 = cm[1], c45 = cm[2], c67 = cm[3];
        const float4* ap = (const float4*)(alpha + i0);
        float4 a0 = ap[0], a1 = ap[1];

        float cx[8] = {c01.x, c01.z, c23.x, c23.z, c45.x, c45.z, c67.x, c67.z};
        float cy[8] = {c01.y, c01.w, c23.y, c23.w, c45.y, c45.w, c67.y, c67.w};
        float av[8] = {a0.x, a0.y, a0.z, a0.w, a1.x, a1.y, a1.z, a1.w};

        bf16x8 w;
#pragma unroll
        for (int j = 0; j < 8; ++j) {
            float d0 = cx[j] - r0;
            float d1 = cy[j] - r1;
            w[j] = (__bf16)(__expf(-(d0 * d0 + d1 * d1)) * av[j]);
        }

        // fragment-order destination
        const int panel = o >> 8, wn = (o >> 6) & 3, nf = (o >> 4) & 3, lr = o & 15;
        const int kt = i0 >> 6, kk = (i0 >> 5) & 1, lh = (i0 >> 3) & 3;
        const size_t idx = (((size_t)(panel * 64 + kt) * 16 + wn * 4 + nf) * 1024)
                         + kk * 512 + (lh * 16 + lr) * 8;
        *(bf16x8*)(Wt2 + idx) = w;
    }
}

// ---------------------------------------------------------------------------
__global__ __launch_bounds__(THREADS, 2) void gemm_kernel(
    const __bf16* __restrict__ Xb,   // [BATCH, IN] bf16
    const __bf16* __restrict__ Wt2,  // fragment-ordered W^T
    float* __restrict__ Out)         // [BATCH, OUT]
{
    __shared__ __align__(16) __bf16 lds[2 * ABUF];   // 64 KiB (A only)

    const int tid  = threadIdx.x;
    const int wave = tid >> 6;
    const int lane = tid & 63;
    const int lh   = lane >> 4;          // 0..3
    const int lr   = lane & 15;
    const int wm   = wave >> 2;          // 0..1  (M waves)
    const int wn   = wave & 3;           // 0..3  (N waves)

    // ---- XCD-aware block swizzle (512 wg, 512%8==0) ----
    const int swz  = (blockIdx.x & 7) * 64 + (blockIdx.x >> 3);
    const int m0   = (swz >> 4) * BM;
    const int n0   = (swz & 15) * BN;

    // ---- A staging (2 loads/thread per unit; swizzled global source) ----
    const __bf16 *pA[2];
    __bf16 *lA[2];
#pragma unroll
    for (int j = 0; j < 2; ++j) {
        const int c  = wave * 64 + lane + j * 512;
        const int rp = c >> 3;
        const int kg = (c & 7) ^ (rp & 7);
        const int rA = ((rp >> 6) & 1) * 128 + (rp & 63);
        pA[j] = Xb + (size_t)(m0 + rA) * IN_DIM + kg * 8;
        lA[j] = lds + j * 4096 + wave * 512;          // wave-uniform dest
    }

    auto STAGE_A = [&](int kt, int h, int b) {
#pragma unroll
        for (int j = 0; j < 2; ++j)
            __builtin_amdgcn_global_load_lds(
                (const __attribute__((address_space(1))) unsigned int*)
                    (pA[j] + (size_t)h * 64 * IN_DIM + kt * BK),
                (__attribute__((address_space(3))) unsigned int*)
                    (lA[j] + b * ABUF + h * UNIT), 16, 0, 0);
    };

    // ---- B fragment pointer (fragment-ordered global, coalesced 1KB/frag) ----
    const __bf16* bPtr = Wt2 + ((size_t)(n0 >> 8) * 64 * 16 + wn * 4) * 1024
                             + lane * 8;
    auto LOADB = [&](int kt, bf16x8 (&bN)[8]) {
#pragma unroll
        for (int nf = 0; nf < 4; ++nf)
#pragma unroll
            for (int kk = 0; kk < 2; ++kk)
                bN[nf * 2 + kk] = *(const bf16x8*)
                    (bPtr + ((size_t)kt * 16 + nf) * 1024 + kk * 512);
    };

    // ---- A fragment read base (swizzled chunks; rho&7 == lr&7) ----
    const int l7  = lr & 7;
    const int sc0 = lh ^ l7;          // kk=0 chunk
    const int sc1 = (4 + lh) ^ l7;    // kk=1 chunk
    const __bf16* aB = lds + (wm * 64 + lr) * 64;

    auto RD_A = [&](int m, int kk, int bo) -> bf16x8 {
        return *(const bf16x8*)(aB + bo + (m >> 2) * UNIT + (m & 3) * 1024
                                + (kk ? sc1 : sc0) * 8);
    };

    f32x4 acc[8][4];
#pragma unroll
    for (int m = 0; m < 8; ++m)
#pragma unroll
        for (int n = 0; n < 4; ++n)
            acc[m][n] = f32x4{0.f, 0.f, 0.f, 0.f};

    bf16x8 bRegA[8], bRegB[8];

    // ---- one-tile body ----
    auto TILE = [&](int t, int BO, bf16x8 (&bCur)[8], bf16x8 (&bNext)[8]) {
        const int kt1 = (t + 1 < KTILES) ? t + 1 : KTILES - 1;  // clamp benign
        const int SB  = (BO == 0) ? 1 : 0;

        LOADB(kt1, bNext);                                  // 8 reg loads
        asm volatile("s_waitcnt vmcnt(8)" ::: "memory");    // B(t)+A(t) landed
        __builtin_amdgcn_s_barrier();
        STAGE_A(kt1, 0, SB);                                // post-barrier: WAR-safe
        STAGE_A(kt1, 1, SB);

        bf16x8 afL[4][2], afH[4][2];
#pragma unroll
        for (int mf = 0; mf < 4; ++mf) {
            afL[mf][0] = RD_A(mf, 0, BO);
            afL[mf][1] = RD_A(mf, 1, BO);
        }
        __builtin_amdgcn_s_setprio(1);
#pragma unroll
        for (int kk = 0; kk < 2; ++kk)
#pragma unroll
            for (int mf = 0; mf < 4; ++mf)
#pragma unroll
                for (int nf = 0; nf < 4; ++nf)
                    acc[mf][nf] = __builtin_amdgcn_mfma_f32_16x16x32_bf16(
                        afL[mf][kk], bCur[nf * 2 + kk], acc[mf][nf], 0, 0, 0);
        __builtin_amdgcn_s_setprio(0);

#pragma unroll
        for (int mf = 0; mf < 4; ++mf) {
            afH[mf][0] = RD_A(4 + mf, 0, BO);
            afH[mf][1] = RD_A(4 + mf, 1, BO);
        }
        __builtin_amdgcn_s_setprio(1);
#pragma unroll
        for (int kk = 0; kk < 2; ++kk)
#pragma unroll
            for (int mf = 0; mf < 4; ++mf)
#pragma unroll
                for (int nf = 0; nf < 4; ++nf)
                    acc[4 + mf][nf] = __builtin_amdgcn_mfma_f32_16x16x32_bf16(
                        afH[mf][kk], bCur[nf * 2 + kk], acc[4 + mf][nf], 0, 0, 0);
        __builtin_amdgcn_s_setprio(0);
    };

    // ---- prologue: A(0) -> buf0, B(0) -> bRegA ----
    STAGE_A(0, 0, 0);
    STAGE_A(0, 1, 0);
    LOADB(0, bRegA);
    asm volatile("s_waitcnt vmcnt(0)" ::: "memory");
    __builtin_amdgcn_s_barrier();

    // ---- main loop: unrolled x2, static reg ping-pong ----
    for (int tt = 0; tt < KTILES; tt += 2) {
        TILE(tt,     0,    bRegA, bRegB);
        TILE(tt + 1, ABUF, bRegB, bRegA);
    }

    // quiesce stray prefetches before CU hand-off
    asm volatile("s_waitcnt vmcnt(0)" ::: "memory");

    // ---- epilogue: C/D layout col=lane&15, row=(lane>>4)*4+j ----
    const int crow = m0 + wm * 128 + lh * 4;
    const int ccol = n0 + wn * 64 + lr;
#pragma unroll
    for (int m = 0; m < 8; ++m)
#pragma unroll
        for (int n = 0; n < 4; ++n) {
            float* o = Out + (size_t)(crow + m * 16) * OUT_DIM + (ccol + n * 16);
#pragma unroll
            for (int j = 0; j < 4; ++j)
                o[(size_t)j * OUT_DIM] = acc[m][n][j];
        }
}

// ---------------------------------------------------------------------------
extern "C" void kernel_launch(void* const* d_in, const int* in_sizes, int n_in,
                              void* d_out, int out_size, void* d_ws, size_t ws_size,
                              hipStream_t stream) {
    const float* x  = (const float*)d_in[0];   // [8192, 4096]
    const float* rm = (const float*)d_in[1];   // [4096, 2]
    const float* cm = (const float*)d_in[2];   // [4096, 2]
    const float* al = (const float*)d_in[3];   // [4096]
    float* out = (float*)d_out;                // [8192, 4096]

    __bf16* Wt2 = (__bf16*)d_ws;                                    // 32 MiB
    __bf16* Xb  = (__bf16*)((char*)d_ws + (size_t)32 * 1024 * 1024); // 64 MiB

    prep_kernel<<<NCONV + NWTB, 256, 0, stream>>>(x, rm, cm, al, Xb, Wt2);

    dim3 g2((BATCH / BM) * (OUT_DIM / BN));    // 512
    gemm_kernel<<<g2, THREADS, 0, stream>>>(Xb, Wt2, out);
}

// Round 18
// 259.008 us; speedup vs baseline: 1.1210x; 1.1210x over previous
//
#include <hip/hip_runtime.h>
#include <hip/hip_bf16.h>
#include <cstdint>
#include <cstddef>

// out[B,OUT] = (x * alpha) @ W,  W[i,o] = exp(-||col_i - row_o||^2)
// B=8192, IN=4096, OUT=4096.  f32 in/out.
//
// FINAL (r18 = r14 verbatim, the measured best of 17 variants):
// k0 (fused prep): x f32 -> bf16 Xb ; Wt[o][i] = alpha[i]*exp(-d2) bf16 (B^T)
// k1: 256x256 GEMM, BK=64, 8 waves (2M x 4N), 16x16x32 MFMA.
//     Schedule = {reads-early, zero-stall counted vmcnt, 1-barrier/phase},
//     K-loop unrolled x2 (compile-time buffer offsets).
//     Measured: GEMM 227us (1211 TF, MfmaUtil 55.3%, 0 bank conflicts),
//     total 258.7us.  Bracketing (all worse): 2-barrier+lgkm variants
//     (251-265), reg-prefetch (240), single-wait deep prefetch (228),
//     wave-drift single-barrier (246), 2 blocks/CU (288/spill), 32x32 MFMA
//     (268, conflicts), B-direct-to-reg (250).  Prep is at its 224MB BW
//     floor (~31us).
//
// Per tile (4 quadrant phases):
//   p0: read bL,afL (12 ds); stage A0+B0(t+1); vmcnt(6); bar; MFMA afL*bL
//   p1: read bH (4);         stage B1(t+1);    vmcnt(6); bar; MFMA afL*bH
//   p2: read afH (8);        stage A1(t+1);              bar; MFMA afH*bL
//   p3: (no reads)                             vmcnt(4); bar; MFMA afH*bH
// Wait algebra (zero-stall): after p3(t-1): {B1(t),A1(t)}=4 outstanding;
//   p0 +4 ->8, vmcnt(6) confirms B1(t) [staged p1(t-1), 3ph, landed];
//   p1 +2 ->8, vmcnt(6) confirms A1(t) [p2(t-1), 3ph]; p2 +2 ->8;
//   p3 vmcnt(4) confirms A0,B0(t+1) [p0(t), 3ph].  RAW: each phase's reads
//   follow the prev phase's confirm+barrier.  WAR: every stage overwrites a
//   slot last read >=4 barriers prior.  Floor 4 in flight.  Prologue
//   vmcnt(4).  Tail: stage indices wrap (&63) -- stages tile-0 data into a
//   never-read buffer (benign).  Trailing vmcnt(0).
// LDS layout (0 conflicts): unit=[128 rows][64 k]; 16B chunk kc of row rho
// stored at kc ^ (rho&7); staging pre-swizzles per-lane GLOBAL addr (LDS dest
// linear per gload_lds rule).

#define IN_DIM  4096
#define OUT_DIM 4096
#define BATCH   8192

#define BM 256
#define BN 256
#define BK 64
#define KTILES (IN_DIM / BK)   // 64
#define THREADS 512

#define UNIT   8192            // elems per stage unit (128 rows * 64)
#define OPOFF  16384           // A (2 units) -> B offset
#define BUFOFF 32768           // elems per buffer (A + B)

#define NCONV  (BATCH * IN_DIM / (256 * 8))   // 16384 convert blocks
#define NWTB   (OUT_DIM * 2)                  // 8192 wt blocks

typedef __bf16 bf16x8 __attribute__((ext_vector_type(8)));
typedef float  f32x4  __attribute__((ext_vector_type(4)));

// ---------------------------------------------------------------------------
// Fused prep: blocks [0,NCONV) convert x; blocks [NCONV, NCONV+NWTB) build Wt.
// ---------------------------------------------------------------------------
__global__ __launch_bounds__(256) void prep_kernel(
    const float* __restrict__ x,
    const float* __restrict__ rows_mean,     // [OUT,2]
    const float* __restrict__ columns_mean,  // [IN,2]
    const float* __restrict__ alpha,         // [IN]
    __bf16* __restrict__ xb,                 // [BATCH][IN]
    __bf16* __restrict__ Wt)                 // [OUT][IN]
{
    const int b = blockIdx.x;
    if (b < NCONV) {
        const size_t i = ((size_t)b * 256 + threadIdx.x) * 8;
        const float4 v0 = *(const float4*)(x + i);
        const float4 v1 = *(const float4*)(x + i + 4);
        bf16x8 o;
        o[0] = (__bf16)v0.x; o[1] = (__bf16)v0.y; o[2] = (__bf16)v0.z; o[3] = (__bf16)v0.w;
        o[4] = (__bf16)v1.x; o[5] = (__bf16)v1.y; o[6] = (__bf16)v1.z; o[7] = (__bf16)v1.w;
        *(bf16x8*)(xb + i) = o;
    } else {
        const int bb = b - NCONV;
        const int o  = bb >> 1;
        const int i0 = ((bb & 1) * 256 + threadIdx.x) * 8;

        const float r0 = rows_mean[2 * o];
        const float r1 = rows_mean[2 * o + 1];

        const float4* cm = (const float4*)(columns_mean + 2 * (size_t)i0);
        float4 c01 = cm[0], c23 = cm[1], c45 = cm[2], c67 = cm[3];
        const float4* ap = (const float4*)(alpha + i0);
        float4 a0 = ap[0], a1 = ap[1];

        float cx[8] = {c01.x, c01.z, c23.x, c23.z, c45.x, c45.z, c67.x, c67.z};
        float cy[8] = {c01.y, c01.w, c23.y, c23.w, c45.y, c45.w, c67.y, c67.w};
        float av[8] = {a0.x, a0.y, a0.z, a0.w, a1.x, a1.y, a1.z, a1.w};

        bf16x8 w;
#pragma unroll
        for (int j = 0; j < 8; ++j) {
            float d0 = cx[j] - r0;
            float d1 = cy[j] - r1;
            w[j] = (__bf16)(__expf(-(d0 * d0 + d1 * d1)) * av[j]);
        }
        *(bf16x8*)(Wt + (size_t)o * IN_DIM + i0) = w;
    }
}

// ---------------------------------------------------------------------------
__global__ __launch_bounds__(THREADS, 2) void gemm_kernel(
    const __bf16* __restrict__ Xb,   // [BATCH, IN] bf16
    const __bf16* __restrict__ Wt,   // [OUT][IN]   bf16 (B^T)
    float* __restrict__ Out)         // [BATCH, OUT]
{
    __shared__ __align__(16) __bf16 lds[2 * BUFOFF];   // 128 KiB

    const int tid  = threadIdx.x;
    const int wave = tid >> 6;
    const int lane = tid & 63;
    const int lh   = lane >> 4;          // 0..3
    const int lr   = lane & 15;
    const int wm   = wave >> 2;          // 0..1  (M waves)
    const int wn   = wave & 3;           // 0..3  (N waves)

    // ---- XCD-aware block swizzle (512 wg, 512%8==0) ----
    const int swz  = (blockIdx.x & 7) * 64 + (blockIdx.x >> 3);
    const int m0   = (swz >> 4) * BM;
    const int n0   = (swz & 15) * BN;

    // ---- staging precompute (2 loads/thread per unit) ----
    const __bf16 *pA[2], *pB[2];
    __bf16 *lA[2], *lB[2];
#pragma unroll
    for (int j = 0; j < 2; ++j) {
        const int c  = wave * 64 + lane + j * 512;
        const int rp = c >> 3;
        const int kg = (c & 7) ^ (rp & 7);
        const int rA = ((rp >> 6) & 1) * 128 + (rp & 63);
        const int rB = (rp >> 5) * 64 + (rp & 31);
        pA[j] = Xb + (size_t)(m0 + rA) * IN_DIM + kg * 8;
        pB[j] = Wt + (size_t)(n0 + rB) * IN_DIM + kg * 8;
        lA[j] = lds + j * 4096 + wave * 512;          // wave-uniform dest
        lB[j] = lds + OPOFF + j * 4096 + wave * 512;
    }

    auto STAGE_A = [&](int kt, int h, int b) {
#pragma unroll
        for (int j = 0; j < 2; ++j)
            __builtin_amdgcn_global_load_lds(
                (const __attribute__((address_space(1))) unsigned int*)
                    (pA[j] + (size_t)h * 64 * IN_DIM + kt * BK),
                (__attribute__((address_space(3))) unsigned int*)
                    (lA[j] + b * BUFOFF + h * UNIT), 16, 0, 0);
    };
    auto STAGE_B = [&](int kt, int h, int b) {
#pragma unroll
        for (int j = 0; j < 2; ++j)
            __builtin_amdgcn_global_load_lds(
                (const __attribute__((address_space(1))) unsigned int*)
                    (pB[j] + (size_t)h * 32 * IN_DIM + kt * BK),
                (__attribute__((address_space(3))) unsigned int*)
                    (lB[j] + b * BUFOFF + h * UNIT), 16, 0, 0);
    };

    // ---- fragment read bases (swizzled chunks; rho&7 == lr&7) ----
    const int l7  = lr & 7;
    const int sc0 = lh ^ l7;          // kk=0 chunk
    const int sc1 = (4 + lh) ^ l7;    // kk=1 chunk
    const __bf16* aB = lds + (wm * 64 + lr) * 64;
    const __bf16* bB = lds + OPOFF + (wn * 32 + lr) * 64;

    auto RD_A = [&](int m, int kk, int bo) -> bf16x8 {
        return *(const bf16x8*)(aB + bo + (m >> 2) * UNIT + (m & 3) * 1024
                                + (kk ? sc1 : sc0) * 8);
    };
    auto RD_B = [&](int n, int kk, int bo) -> bf16x8 {
        return *(const bf16x8*)(bB + bo + (n >> 1) * UNIT + (n & 1) * 1024
                                + (kk ? sc1 : sc0) * 8);
    };

    f32x4 acc[8][4];
#pragma unroll
    for (int m = 0; m < 8; ++m)
#pragma unroll
        for (int n = 0; n < 4; ++n)
            acc[m][n] = f32x4{0.f, 0.f, 0.f, 0.f};

    // ---- one-tile body (BO/SB compile-time) ----
    auto TILE = [&](int t, int BO, int SB) {
        const int kt1 = (t + 1) & 63;    // wrap benign (never-read buffer)

        bf16x8 afL[4][2], afH[4][2], bL[4], bH[4];

        // p0: reads bL+afL; stage A0+B0(t+1); vmcnt(6); bar; MFMA afL*bL
        bL[0] = RD_B(0, 0, BO); bL[1] = RD_B(0, 1, BO);
        bL[2] = RD_B(1, 0, BO); bL[3] = RD_B(1, 1, BO);
#pragma unroll
        for (int mf = 0; mf < 4; ++mf) {
            afL[mf][0] = RD_A(mf, 0, BO);
            afL[mf][1] = RD_A(mf, 1, BO);
        }
        STAGE_A(kt1, 0, SB);
        STAGE_B(kt1, 0, SB);
        asm volatile("s_waitcnt vmcnt(6)" ::: "memory");   // confirm B1(t)
        __builtin_amdgcn_s_barrier();
        __builtin_amdgcn_s_setprio(1);
#pragma unroll
        for (int kk = 0; kk < 2; ++kk)
#pragma unroll
            for (int mf = 0; mf < 4; ++mf)
#pragma unroll
                for (int nf = 0; nf < 2; ++nf)
                    acc[mf][nf] = __builtin_amdgcn_mfma_f32_16x16x32_bf16(
                        afL[mf][kk], bL[nf * 2 + kk], acc[mf][nf], 0, 0, 0);
        __builtin_amdgcn_s_setprio(0);

        // p1: reads bH; stage B1(t+1); vmcnt(6); bar; MFMA afL*bH
        bH[0] = RD_B(2, 0, BO); bH[1] = RD_B(2, 1, BO);
        bH[2] = RD_B(3, 0, BO); bH[3] = RD_B(3, 1, BO);
        STAGE_B(kt1, 1, SB);
        asm volatile("s_waitcnt vmcnt(6)" ::: "memory");   // confirm A1(t)
        __builtin_amdgcn_s_barrier();
        __builtin_amdgcn_s_setprio(1);
#pragma unroll
        for (int kk = 0; kk < 2; ++kk)
#pragma unroll
            for (int mf = 0; mf < 4; ++mf)
#pragma unroll
                for (int nf = 0; nf < 2; ++nf)
                    acc[mf][2 + nf] = __builtin_amdgcn_mfma_f32_16x16x32_bf16(
                        afL[mf][kk], bH[nf * 2 + kk], acc[mf][2 + nf], 0, 0, 0);
        __builtin_amdgcn_s_setprio(0);

        // p2: reads afH; stage A1(t+1); no wait; bar; MFMA afH*bL
#pragma unroll
        for (int mf = 0; mf < 4; ++mf) {
            afH[mf][0] = RD_A(4 + mf, 0, BO);
            afH[mf][1] = RD_A(4 + mf, 1, BO);
        }
        STAGE_A(kt1, 1, SB);
        __builtin_amdgcn_s_barrier();
        __builtin_amdgcn_s_setprio(1);
#pragma unroll
        for (int kk = 0; kk < 2; ++kk)
#pragma unroll
            for (int mf = 0; mf < 4; ++mf)
#pragma unroll
                for (int nf = 0; nf < 2; ++nf)
                    acc[4 + mf][nf] = __builtin_amdgcn_mfma_f32_16x16x32_bf16(
                        afH[mf][kk], bL[nf * 2 + kk], acc[4 + mf][nf], 0, 0, 0);
        __builtin_amdgcn_s_setprio(0);

        // p3: no reads; vmcnt(4) [confirm A0,B0(t+1)]; bar; MFMA afH*bH
        asm volatile("s_waitcnt vmcnt(4)" ::: "memory");
        __builtin_amdgcn_s_barrier();
        __builtin_amdgcn_s_setprio(1);
#pragma unroll
        for (int kk = 0; kk < 2; ++kk)
#pragma unroll
            for (int mf = 0; mf < 4; ++mf)
#pragma unroll
                for (int nf = 0; nf < 2; ++nf)
                    acc[4 + mf][2 + nf] = __builtin_amdgcn_mfma_f32_16x16x32_bf16(
                        afH[mf][kk], bH[nf * 2 + kk], acc[4 + mf][2 + nf], 0, 0, 0);
        __builtin_amdgcn_s_setprio(0);
    };

    // ---- prologue: tile 0 (4 units) -> buf0; confirm A0,B0(0) only ----
    STAGE_A(0, 0, 0); STAGE_B(0, 0, 0); STAGE_B(0, 1, 0); STAGE_A(0, 1, 0);
    asm volatile("s_waitcnt vmcnt(4)" ::: "memory");   // A0(0),B0(0) landed
    __builtin_amdgcn_s_barrier();

    // ---- main loop: unrolled x2, compile-time buffer offsets ----
    for (int tt = 0; tt < KTILES; tt += 2) {
        TILE(tt,     0,      1);   // even tile: read buf0, stage buf1
        TILE(tt + 1, BUFOFF, 0);   // odd  tile: read buf1, stage buf0
    }

    // quiesce stray prefetches before CU hand-off
    asm volatile("s_waitcnt vmcnt(0)" ::: "memory");

    // ---- epilogue: C/D layout col=lane&15, row=(lane>>4)*4+j ----
    const int crow = m0 + wm * 128 + lh * 4;
    const int ccol = n0 + wn * 64 + lr;
#pragma unroll
    for (int m = 0; m < 8; ++m)
#pragma unroll
        for (int n = 0; n < 4; ++n) {
            float* o = Out + (size_t)(crow + m * 16) * OUT_DIM + (ccol + n * 16);
#pragma unroll
            for (int j = 0; j < 4; ++j)
                o[(size_t)j * OUT_DIM] = acc[m][n][j];
        }
}

// ---------------------------------------------------------------------------
extern "C" void kernel_launch(void* const* d_in, const int* in_sizes, int n_in,
                              void* d_out, int out_size, void* d_ws, size_t ws_size,
                              hipStream_t stream) {
    const float* x  = (const float*)d_in[0];   // [8192, 4096]
    const float* rm = (const float*)d_in[1];   // [4096, 2]
    const float* cm = (const float*)d_in[2];   // [4096, 2]
    const float* al = (const float*)d_in[3];   // [4096]
    float* out = (float*)d_out;                // [8192, 4096]

    __bf16* Wt = (__bf16*)d_ws;                                     // 32 MiB
    __bf16* Xb = (__bf16*)((char*)d_ws + (size_t)32 * 1024 * 1024); // 64 MiB

    prep_kernel<<<NCONV + NWTB, 256, 0, stream>>>(x, rm, cm, al, Xb, Wt);

    dim3 g2((BATCH / BM) * (OUT_DIM / BN));    // 512
    gemm_kernel<<<g2, THREADS, 0, stream>>>(Xb, Wt, out);
}

// Round 19
// 258.406 us; speedup vs baseline: 1.1236x; 1.0023x over previous
//
#include <hip/hip_runtime.h>
#include <hip/hip_bf16.h>
#include <cstdint>
#include <cstddef>

// out[B,OUT] = (x * alpha) @ W,  W[i,o] = exp(-||col_i - row_o||^2)
// B=8192, IN=4096, OUT=4096.  f32 in/out.
//
// r19 = r14/r18 (best: GEMM 222us, 1238 TF, MfmaUtil 57%) with the ONE
// provably-redundant barrier removed (4 -> 3 barriers/tile).  Confirm-
// mutuality requires exactly one barrier after each counted vmcnt (p0->B1,
// p1->A1, p3->A0B0); p2's leading barrier served neither confirm nor WAR
// (stage A1(t+1)@p2(t) vs last read p2(t-1): >=3 intervening barriers
// remain).  Removing it lets p2's 8 afH reads + stage drain UNDER p1's MFMA
// cluster in the merged window.
//
// Per tile (3 barriers):
//   p0: read bL,afL (12 ds); stage A0+B0(t+1); vmcnt(6); BAR; MFMA afL*bL
//   p1: read bH (4);         stage B1(t+1);    vmcnt(6); BAR; MFMA afL*bH
//   p2: read afH (8);        stage A1(t+1);    [no bar]      MFMA afH*bL
//   p3:                                        vmcnt(4); BAR; MFMA afH*bH
// Wait algebra (zero-stall, unchanged from r14): after p3(t-1):
//   {B1(t),A1(t)}=4 outstanding; p0 +4 ->8, vmcnt(6) confirms B1(t) [staged
//   p1(t-1), 3ph]; p1 +2 ->8, vmcnt(6) confirms A1(t) [p2(t-1), 3ph];
//   p2 +2 ->8; p3 vmcnt(4) confirms A0,B0(t+1) [p0(t), 3ph].
// RAW: every confirm has vmcnt + barrier before the cross-wave reads
//   (B1: p0-bar before p1 reads; A1: p1-bar before p2 reads; A0B0: p3-bar
//   before p0(t+1) reads).  WAR: A0B0 stage vs last read: 2 barriers; B1: 2;
//   A1: 3.  Floor 4 in flight.  Prologue vmcnt(4).  Tail: stage indices wrap
//   (&63) into a never-read buffer (benign).  Trailing vmcnt(0).
// LDS layout (0 conflicts): unit=[128 rows][64 k]; 16B chunk kc of row rho
// stored at kc ^ (rho&7); staging pre-swizzles per-lane GLOBAL addr (LDS dest
// linear per gload_lds rule).

#define IN_DIM  4096
#define OUT_DIM 4096
#define BATCH   8192

#define BM 256
#define BN 256
#define BK 64
#define KTILES (IN_DIM / BK)   // 64
#define THREADS 512

#define UNIT   8192            // elems per stage unit (128 rows * 64)
#define OPOFF  16384           // A (2 units) -> B offset
#define BUFOFF 32768           // elems per buffer (A + B)

#define NCONV  (BATCH * IN_DIM / (256 * 8))   // 16384 convert blocks
#define NWTB   (OUT_DIM * 2)                  // 8192 wt blocks

typedef __bf16 bf16x8 __attribute__((ext_vector_type(8)));
typedef float  f32x4  __attribute__((ext_vector_type(4)));

// ---------------------------------------------------------------------------
// Fused prep: blocks [0,NCONV) convert x; blocks [NCONV, NCONV+NWTB) build Wt.
// ---------------------------------------------------------------------------
__global__ __launch_bounds__(256) void prep_kernel(
    const float* __restrict__ x,
    const float* __restrict__ rows_mean,     // [OUT,2]
    const float* __restrict__ columns_mean,  // [IN,2]
    const float* __restrict__ alpha,         // [IN]
    __bf16* __restrict__ xb,                 // [BATCH][IN]
    __bf16* __restrict__ Wt)                 // [OUT][IN]
{
    const int b = blockIdx.x;
    if (b < NCONV) {
        const size_t i = ((size_t)b * 256 + threadIdx.x) * 8;
        const float4 v0 = *(const float4*)(x + i);
        const float4 v1 = *(const float4*)(x + i + 4);
        bf16x8 o;
        o[0] = (__bf16)v0.x; o[1] = (__bf16)v0.y; o[2] = (__bf16)v0.z; o[3] = (__bf16)v0.w;
        o[4] = (__bf16)v1.x; o[5] = (__bf16)v1.y; o[6] = (__bf16)v1.z; o[7] = (__bf16)v1.w;
        *(bf16x8*)(xb + i) = o;
    } else {
        const int bb = b - NCONV;
        const int o  = bb >> 1;
        const int i0 = ((bb & 1) * 256 + threadIdx.x) * 8;

        const float r0 = rows_mean[2 * o];
        const float r1 = rows_mean[2 * o + 1];

        const float4* cm = (const float4*)(columns_mean + 2 * (size_t)i0);
        float4 c01 = cm[0], c23 = cm[1], c45 = cm[2], c67 = cm[3];
        const float4* ap = (const float4*)(alpha + i0);
        float4 a0 = ap[0], a1 = ap[1];

        float cx[8] = {c01.x, c01.z, c23.x, c23.z, c45.x, c45.z, c67.x, c67.z};
        float cy[8] = {c01.y, c01.w, c23.y, c23.w, c45.y, c45.w, c67.y, c67.w};
        float av[8] = {a0.x, a0.y, a0.z, a0.w, a1.x, a1.y, a1.z, a1.w};

        bf16x8 w;
#pragma unroll
        for (int j = 0; j < 8; ++j) {
            float d0 = cx[j] - r0;
            float d1 = cy[j] - r1;
            w[j] = (__bf16)(__expf(-(d0 * d0 + d1 * d1)) * av[j]);
        }
        *(bf16x8*)(Wt + (size_t)o * IN_DIM + i0) = w;
    }
}

// ---------------------------------------------------------------------------
__global__ __launch_bounds__(THREADS, 2) void gemm_kernel(
    const __bf16* __restrict__ Xb,   // [BATCH, IN] bf16
    const __bf16* __restrict__ Wt,   // [OUT][IN]   bf16 (B^T)
    float* __restrict__ Out)         // [BATCH, OUT]
{
    __shared__ __align__(16) __bf16 lds[2 * BUFOFF];   // 128 KiB

    const int tid  = threadIdx.x;
    const int wave = tid >> 6;
    const int lane = tid & 63;
    const int lh   = lane >> 4;          // 0..3
    const int lr   = lane & 15;
    const int wm   = wave >> 2;          // 0..1  (M waves)
    const int wn   = wave & 3;           // 0..3  (N waves)

    // ---- XCD-aware block swizzle (512 wg, 512%8==0) ----
    const int swz  = (blockIdx.x & 7) * 64 + (blockIdx.x >> 3);
    const int m0   = (swz >> 4) * BM;
    const int n0   = (swz & 15) * BN;

    // ---- staging precompute (2 loads/thread per unit) ----
    const __bf16 *pA[2], *pB[2];
    __bf16 *lA[2], *lB[2];
#pragma unroll
    for (int j = 0; j < 2; ++j) {
        const int c  = wave * 64 + lane + j * 512;
        const int rp = c >> 3;
        const int kg = (c & 7) ^ (rp & 7);
        const int rA = ((rp >> 6) & 1) * 128 + (rp & 63);
        const int rB = (rp >> 5) * 64 + (rp & 31);
        pA[j] = Xb + (size_t)(m0 + rA) * IN_DIM + kg * 8;
        pB[j] = Wt + (size_t)(n0 + rB) * IN_DIM + kg * 8;
        lA[j] = lds + j * 4096 + wave * 512;          // wave-uniform dest
        lB[j] = lds + OPOFF + j * 4096 + wave * 512;
    }

    auto STAGE_A = [&](int kt, int h, int b) {
#pragma unroll
        for (int j = 0; j < 2; ++j)
            __builtin_amdgcn_global_load_lds(
                (const __attribute__((address_space(1))) unsigned int*)
                    (pA[j] + (size_t)h * 64 * IN_DIM + kt * BK),
                (__attribute__((address_space(3))) unsigned int*)
                    (lA[j] + b * BUFOFF + h * UNIT), 16, 0, 0);
    };
    auto STAGE_B = [&](int kt, int h, int b) {
#pragma unroll
        for (int j = 0; j < 2; ++j)
            __builtin_amdgcn_global_load_lds(
                (const __attribute__((address_space(1))) unsigned int*)
                    (pB[j] + (size_t)h * 32 * IN_DIM + kt * BK),
                (__attribute__((address_space(3))) unsigned int*)
                    (lB[j] + b * BUFOFF + h * UNIT), 16, 0, 0);
    };

    // ---- fragment read bases (swizzled chunks; rho&7 == lr&7) ----
    const int l7  = lr & 7;
    const int sc0 = lh ^ l7;          // kk=0 chunk
    const int sc1 = (4 + lh) ^ l7;    // kk=1 chunk
    const __bf16* aB = lds + (wm * 64 + lr) * 64;
    const __bf16* bB = lds + OPOFF + (wn * 32 + lr) * 64;

    auto RD_A = [&](int m, int kk, int bo) -> bf16x8 {
        return *(const bf16x8*)(aB + bo + (m >> 2) * UNIT + (m & 3) * 1024
                                + (kk ? sc1 : sc0) * 8);
    };
    auto RD_B = [&](int n, int kk, int bo) -> bf16x8 {
        return *(const bf16x8*)(bB + bo + (n >> 1) * UNIT + (n & 1) * 1024
                                + (kk ? sc1 : sc0) * 8);
    };

    f32x4 acc[8][4];
#pragma unroll
    for (int m = 0; m < 8; ++m)
#pragma unroll
        for (int n = 0; n < 4; ++n)
            acc[m][n] = f32x4{0.f, 0.f, 0.f, 0.f};

    // ---- one-tile body (BO/SB compile-time) ----
    auto TILE = [&](int t, int BO, int SB) {
        const int kt1 = (t + 1) & 63;    // wrap benign (never-read buffer)

        bf16x8 afL[4][2], afH[4][2], bL[4], bH[4];

        // p0: reads bL+afL; stage A0+B0(t+1); vmcnt(6); BAR; MFMA afL*bL
        bL[0] = RD_B(0, 0, BO); bL[1] = RD_B(0, 1, BO);
        bL[2] = RD_B(1, 0, BO); bL[3] = RD_B(1, 1, BO);
#pragma unroll
        for (int mf = 0; mf < 4; ++mf) {
            afL[mf][0] = RD_A(mf, 0, BO);
            afL[mf][1] = RD_A(mf, 1, BO);
        }
        STAGE_A(kt1, 0, SB);
        STAGE_B(kt1, 0, SB);
        asm volatile("s_waitcnt vmcnt(6)" ::: "memory");   // confirm B1(t)
        __builtin_amdgcn_s_barrier();
        __builtin_amdgcn_s_setprio(1);
#pragma unroll
        for (int kk = 0; kk < 2; ++kk)
#pragma unroll
            for (int mf = 0; mf < 4; ++mf)
#pragma unroll
                for (int nf = 0; nf < 2; ++nf)
                    acc[mf][nf] = __builtin_amdgcn_mfma_f32_16x16x32_bf16(
                        afL[mf][kk], bL[nf * 2 + kk], acc[mf][nf], 0, 0, 0);
        __builtin_amdgcn_s_setprio(0);

        // p1: reads bH; stage B1(t+1); vmcnt(6); BAR; MFMA afL*bH
        bH[0] = RD_B(2, 0, BO); bH[1] = RD_B(2, 1, BO);
        bH[2] = RD_B(3, 0, BO); bH[3] = RD_B(3, 1, BO);
        STAGE_B(kt1, 1, SB);
        asm volatile("s_waitcnt vmcnt(6)" ::: "memory");   // confirm A1(t)
        __builtin_amdgcn_s_barrier();
        __builtin_amdgcn_s_setprio(1);
#pragma unroll
        for (int kk = 0; kk < 2; ++kk)
#pragma unroll
            for (int mf = 0; mf < 4; ++mf)
#pragma unroll
                for (int nf = 0; nf < 2; ++nf)
                    acc[mf][2 + nf] = __builtin_amdgcn_mfma_f32_16x16x32_bf16(
                        afL[mf][kk], bH[nf * 2 + kk], acc[mf][2 + nf], 0, 0, 0);
        __builtin_amdgcn_s_setprio(0);

        // p2: reads afH; stage A1(t+1); NO BARRIER; MFMA afH*bL
        //     (merged window: these reads drain under p1's MFMA cluster)
#pragma unroll
        for (int mf = 0; mf < 4; ++mf) {
            afH[mf][0] = RD_A(4 + mf, 0, BO);
            afH[mf][1] = RD_A(4 + mf, 1, BO);
        }
        STAGE_A(kt1, 1, SB);
        __builtin_amdgcn_s_setprio(1);
#pragma unroll
        for (int kk = 0; kk < 2; ++kk)
#pragma unroll
            for (int mf = 0; mf < 4; ++mf)
#pragma unroll
                for (int nf = 0; nf < 2; ++nf)
                    acc[4 + mf][nf] = __builtin_amdgcn_mfma_f32_16x16x32_bf16(
                        afH[mf][kk], bL[nf * 2 + kk], acc[4 + mf][nf], 0, 0, 0);
        __builtin_amdgcn_s_setprio(0);

        // p3: vmcnt(4) [confirm A0,B0(t+1)]; BAR; MFMA afH*bH
        asm volatile("s_waitcnt vmcnt(4)" ::: "memory");
        __builtin_amdgcn_s_barrier();
        __builtin_amdgcn_s_setprio(1);
#pragma unroll
        for (int kk = 0; kk < 2; ++kk)
#pragma unroll
            for (int mf = 0; mf < 4; ++mf)
#pragma unroll
                for (int nf = 0; nf < 2; ++nf)
                    acc[4 + mf][2 + nf] = __builtin_amdgcn_mfma_f32_16x16x32_bf16(
                        afH[mf][kk], bH[nf * 2 + kk], acc[4 + mf][2 + nf], 0, 0, 0);
        __builtin_amdgcn_s_setprio(0);
    };

    // ---- prologue: tile 0 (4 units) -> buf0; confirm A0,B0(0) only ----
    STAGE_A(0, 0, 0); STAGE_B(0, 0, 0); STAGE_B(0, 1, 0); STAGE_A(0, 1, 0);
    asm volatile("s_waitcnt vmcnt(4)" ::: "memory");   // A0(0),B0(0) landed
    __builtin_amdgcn_s_barrier();

    // ---- main loop: unrolled x2, compile-time buffer offsets ----
    for (int tt = 0; tt < KTILES; tt += 2) {
        TILE(tt,     0,      1);   // even tile: read buf0, stage buf1
        TILE(tt + 1, BUFOFF, 0);   // odd  tile: read buf1, stage buf0
    }

    // quiesce stray prefetches before CU hand-off
    asm volatile("s_waitcnt vmcnt(0)" ::: "memory");

    // ---- epilogue: C/D layout col=lane&15, row=(lane>>4)*4+j ----
    const int crow = m0 + wm * 128 + lh * 4;
    const int ccol = n0 + wn * 64 + lr;
#pragma unroll
    for (int m = 0; m < 8; ++m)
#pragma unroll
        for (int n = 0; n < 4; ++n) {
            float* o = Out + (size_t)(crow + m * 16) * OUT_DIM + (ccol + n * 16);
#pragma unroll
            for (int j = 0; j < 4; ++j)
                o[(size_t)j * OUT_DIM] = acc[m][n][j];
        }
}

// ---------------------------------------------------------------------------
extern "C" void kernel_launch(void* const* d_in, const int* in_sizes, int n_in,
                              void* d_out, int out_size, void* d_ws, size_t ws_size,
                              hipStream_t stream) {
    const float* x  = (const float*)d_in[0];   // [8192, 4096]
    const float* rm = (const float*)d_in[1];   // [4096, 2]
    const float* cm = (const float*)d_in[2];   // [4096, 2]
    const float* al = (const float*)d_in[3];   // [4096]
    float* out = (float*)d_out;                // [8192, 4096]

    __bf16* Wt = (__bf16*)d_ws;                                     // 32 MiB
    __bf16* Xb = (__bf16*)((char*)d_ws + (size_t)32 * 1024 * 1024); // 64 MiB

    prep_kernel<<<NCONV + NWTB, 256, 0, stream>>>(x, rm, cm, al, Xb, Wt);

    dim3 g2((BATCH / BM) * (OUT_DIM / BN));    // 512
    gemm_kernel<<<g2, THREADS, 0, stream>>>(Xb, Wt, out);
}